// Round 4
// baseline (229.705 us; speedup 1.0000x reference)
//
#include <hip/hip_runtime.h>
#include <hip/hip_bf16.h>
#include <hip/hip_cooperative_groups.h>
#include <math.h>

namespace cg = cooperative_groups;

// S5 SSM layer, fully fused. B_SZ=16, L=1024, H=256, P=256.
// One cooperative kernel, 512 blocks (one per 32-row chunk, 2 blocks/CU):
//   phase 0: build W1T/W2T           -> grid.sync
//   phase 1: GEMM1 (u@B_bar^T) -> LDS X -> local scan in LDS -> CEND
//            -> grid.sync
//   phase 2: own exclusive chunk-carry from CEND (<=31 complex FMA)
//   phase 3: fixup X in LDS (x += lam^{j+1} * carry)
//   phase 4: GEMM2 (X@W2T^T) + D*u epilogue -> out
// xs NEVER goes to HBM; only CEND (1 MB) crosses blocks.
#define BB     16
#define LSEQ   1024
#define HH     256
#define PP     256
#define LC     32
#define NC     (LSEQ/LC)     // 32
#define NCHUNK (BB*NC)       // 512

// workspace byte offsets
#define OFF_W1T  0u          // [512][256] bf16: row 2p=Re(B_bar[p][.]), 2p+1=Im
#define OFF_W2T  262144u     // [256][512] bf16: row h, k=2p -> 2*C_re, 2p+1 -> -2*C_im
#define OFF_CEND 524288u     // [512][256] float2 chunk-end states
// total ws use: 1.5 MB

// LDS layout (51712 B total):
//   [0,2048)        As   : 32x32 bf16 A-tile (phase 1)
//   [2048,35328)    Bs/X : phase1 B-staging 512x32 bf16 (32768) UNION
//                          X 32 rows x 520 bf16 (stride-padded, 33280)
//   [35328,51712)   Bs2  : phase4 B-staging 256x32 bf16 (16384)
#define XSTRIDE 520   // bf16 elements per X row (512 + 8 pad -> 2-way-free banks)

typedef __attribute__((ext_vector_type(8))) short short8;
typedef __attribute__((ext_vector_type(4))) float floatx4;

__device__ __forceinline__ float bf2f(unsigned hs) {
    union { unsigned u; float f; } v; v.u = hs << 16; return v.f;
}
__device__ __forceinline__ unsigned short f2bs(float f) {
    __hip_bfloat16 h = __float2bfloat16(f);
    union { __hip_bfloat16 h; unsigned short s; } v; v.h = h; return v.s;
}
__device__ __forceinline__ unsigned packbf(float r, float i) {
    return (unsigned)f2bs(r) | ((unsigned)f2bs(i) << 16);
}
__device__ __forceinline__ void async16(const void* g, void* l) {
    __builtin_amdgcn_global_load_lds(
        (const __attribute__((address_space(1))) unsigned*)g,
        (__attribute__((address_space(3))) unsigned*)l, 16, 0, 0);
}
__device__ __forceinline__ float2 lam_pow(float lr, float li, float dtt) {
    float m = expf(lr * dtt);
    return make_float2(m * cosf(li * dtt), m * sinf(li * dtt));
}

__global__ __launch_bounds__(256, 2) void k_fused(
        const float* __restrict__ u, const float* __restrict__ Lr,
        const float* __restrict__ Li, const float* __restrict__ Bm,
        const float* __restrict__ Cm, const float* __restrict__ D,
        const float* __restrict__ ls, float* __restrict__ out,
        char* __restrict__ ws) {
    cg::grid_group grid = cg::this_grid();
    __shared__ char smem[51712];
    unsigned short* As = (unsigned short*)smem;
    char*           Bs = smem + 2048;
    unsigned short* X  = (unsigned short*)(smem + 2048);   // stride XSTRIDE
    unsigned*      X32 = (unsigned*)(smem + 2048);         // stride XSTRIDE/2
    char*          Bs2 = smem + 35328;

    const int tid = threadIdx.x, bc = blockIdx.x;
    const int wave = tid >> 6, lane = tid & 63;
    const int q = lane >> 4, rr = lane & 15;
    const int c4 = lane & 3, r4 = lane >> 2;

    // ---------------- phase 0: weights ----------------
    if (bc < 256) {
        int p = bc, h = tid;
        float lr0 = Lr[p], li0 = Li[p];
        float dt0 = expf(ls[p]);
        float2 lam0 = lam_pow(lr0, li0, dt0);
        float den = lr0 * lr0 + li0 * li0;
        float nr = lam0.x - 1.0f, ni = lam0.y;
        float cr = (nr * lr0 + ni * li0) / den;     // (lam_bar-1)/Lambda
        float ci = (ni * lr0 - nr * li0) / den;
        float br = Bm[(p * HH + h) * 2 + 0];
        float bi = Bm[(p * HH + h) * 2 + 1];
        unsigned short* w1 = (unsigned short*)(ws + OFF_W1T);
        w1[(2 * p) * 256 + h]     = f2bs(cr * br - ci * bi);
        w1[(2 * p + 1) * 256 + h] = f2bs(cr * bi + ci * br);
    } else {
        int h = bc - 256, p = tid;
        float c_r = Cm[(h * PP + p) * 2 + 0];
        float c_i = Cm[(h * PP + p) * 2 + 1];
        ((unsigned*)(ws + OFF_W2T))[h * 256 + p] = packbf(2.0f * c_r, -2.0f * c_i);
    }
    grid.sync();

    // ---------------- phase 1: GEMM1 for chunk bc ----------------
    const int m0 = bc * LC;
    const unsigned short* W1 = (const unsigned short*)(ws + OFF_W1T);
    floatx4 acc[2][8];
    #pragma unroll
    for (int i = 0; i < 2; ++i)
        #pragma unroll
        for (int j = 0; j < 8; ++j) acc[i][j] = (floatx4)0.0f;

    const int urow = tid >> 3, ucol = (tid & 7) * 4;
    for (int k0 = 0; k0 < 256; k0 += 32) {
        __syncthreads();
        float4 v = *(const float4*)(u + (size_t)(m0 + urow) * 256 + k0 + ucol);
        *(uint2*)((char*)As + urow * 64 + ucol * 2) =
            make_uint2(packbf(v.x, v.y), packbf(v.z, v.w));
        #pragma unroll
        for (int t = wave; t < 32; t += 4)
            async16(W1 + (size_t)(t * 16 + r4) * 256 + k0 + c4 * 8,
                    Bs + t * 1024 + lane * 16);
        __syncthreads();
        short8 a0 = *(const short8*)((char*)As + rr * 64 + q * 16);
        short8 a1 = *(const short8*)((char*)As + (16 + rr) * 64 + q * 16);
        #pragma unroll
        for (int j = 0; j < 8; ++j) {
            short8 b = *(const short8*)(Bs + ((wave * 8 + j) * 16 + rr) * 64 + q * 16);
            acc[0][j] = __builtin_amdgcn_mfma_f32_16x16x32_bf16(a0, b, acc[0][j], 0, 0, 0);
            acc[1][j] = __builtin_amdgcn_mfma_f32_16x16x32_bf16(a1, b, acc[1][j], 0, 0, 0);
        }
    }
    __syncthreads();
    // dump Bu tile (32 x 512) into X (bf16, padded stride)
    #pragma unroll
    for (int i = 0; i < 2; ++i)
        #pragma unroll
        for (int j = 0; j < 8; ++j)
            #pragma unroll
            for (int r0 = 0; r0 < 4; ++r0)
                X[(i * 16 + q * 4 + r0) * XSTRIDE + wave * 128 + j * 16 + rr] =
                    f2bs(acc[i][j][r0]);
    __syncthreads();

    // local chunk scan in LDS: thread p owns channel pair (2p, 2p+1)
    const int p = tid;
    const float lr = Lr[p], li = Li[p];
    const float dt = expf(ls[p]);
    const float2 lam = lam_pow(lr, li, dt);
    float xr = 0.0f, xi = 0.0f;
    for (int j = 0; j < LC; ++j) {
        unsigned cv = X32[j * (XSTRIDE / 2) + p];
        float br = bf2f(cv & 0xffffu), bi = bf2f(cv >> 16);
        float nr = fmaf(lam.x, xr, fmaf(-lam.y, xi, br));
        float ni = fmaf(lam.x, xi, fmaf(lam.y, xr, bi));
        xr = nr; xi = ni;
        X32[j * (XSTRIDE / 2) + p] = packbf(xr, xi);
    }
    ((float2*)(ws + OFF_CEND))[bc * 256 + p] = make_float2(xr, xi);

    grid.sync();

    // ---------------- phase 2: own exclusive chunk carry ----------------
    const int b = bc >> 5, c = bc & (NC - 1);
    const float2 g = lam_pow(lr, li, dt * (float)LC);   // lambda^LC
    const float2* cend = (const float2*)(ws + OFF_CEND);
    float sr = 0.0f, si = 0.0f;
    for (int cc = 0; cc < c; ++cc) {
        float2 e = cend[(b * NC + cc) * 256 + p];
        float nr = g.x * sr - g.y * si + e.x;
        float ni = g.x * si + g.y * sr + e.y;
        sr = nr; si = ni;
    }

    // ---------------- phase 3: fixup X in LDS ----------------
    float pr = lam.x, pi = lam.y;   // lambda^{j+1}
    for (int j = 0; j < LC; ++j) {
        float ar = pr * sr - pi * si;
        float ai = pr * si + pi * sr;
        unsigned v = X32[j * (XSTRIDE / 2) + p];
        X32[j * (XSTRIDE / 2) + p] = packbf(bf2f(v & 0xffffu) + ar,
                                            bf2f(v >> 16) + ai);
        float nr = pr * lam.x - pi * lam.y;
        pi = pr * lam.y + pi * lam.x; pr = nr;
    }
    __syncthreads();

    // ---------------- phase 4: GEMM2 (X @ W2T^T) + D*u ----------------
    const unsigned short* W2 = (const unsigned short*)(ws + OFF_W2T);
    floatx4 acc2[2][4];
    #pragma unroll
    for (int i = 0; i < 2; ++i)
        #pragma unroll
        for (int j = 0; j < 4; ++j) acc2[i][j] = (floatx4)0.0f;

    for (int k0 = 0; k0 < 512; k0 += 32) {
        __syncthreads();
        #pragma unroll
        for (int t = wave; t < 16; t += 4)
            async16(W2 + (size_t)(t * 16 + r4) * 512 + k0 + c4 * 8,
                    Bs2 + t * 1024 + lane * 16);
        __syncthreads();
        short8 a0 = *(const short8*)((char*)X + rr * (XSTRIDE * 2) + k0 * 2 + q * 16);
        short8 a1 = *(const short8*)((char*)X + (16 + rr) * (XSTRIDE * 2) + k0 * 2 + q * 16);
        #pragma unroll
        for (int j = 0; j < 4; ++j) {
            short8 bfr = *(const short8*)(Bs2 + ((wave * 4 + j) * 16 + rr) * 64 + q * 16);
            acc2[0][j] = __builtin_amdgcn_mfma_f32_16x16x32_bf16(a0, bfr, acc2[0][j], 0, 0, 0);
            acc2[1][j] = __builtin_amdgcn_mfma_f32_16x16x32_bf16(a1, bfr, acc2[1][j], 0, 0, 0);
        }
    }

    #pragma unroll
    for (int i = 0; i < 2; ++i) {
        #pragma unroll
        for (int j = 0; j < 4; ++j) {
            int col = wave * 64 + j * 16 + rr;
            #pragma unroll
            for (int r0 = 0; r0 < 4; ++r0) {
                int row = m0 + i * 16 + q * 4 + r0;
                size_t gi = (size_t)row * 256 + col;
                out[gi] = acc2[i][j][r0] + D[col] * u[gi];
            }
        }
    }
}

extern "C" void kernel_launch(void* const* d_in, const int* in_sizes, int n_in,
                              void* d_out, int out_size, void* d_ws, size_t ws_size,
                              hipStream_t stream) {
    const float* u  = (const float*)d_in[0];
    const float* Lr = (const float*)d_in[1];
    const float* Li = (const float*)d_in[2];
    const float* Bm = (const float*)d_in[3];
    const float* Cm = (const float*)d_in[4];
    const float* D  = (const float*)d_in[5];
    const float* ls = (const float*)d_in[6];
    float* out = (float*)d_out;
    char* ws = (char*)d_ws;

    void* args[] = {(void*)&u, (void*)&Lr, (void*)&Li, (void*)&Bm, (void*)&Cm,
                    (void*)&D, (void*)&ls, (void*)&out, (void*)&ws};
    hipLaunchCooperativeKernel((const void*)k_fused, dim3(NCHUNK), dim3(256),
                               args, 0, stream);
}

// Round 5
// 122.720 us; speedup vs baseline: 1.8718x; 1.8718x over previous
//
#include <hip/hip_runtime.h>
#include <hip/hip_bf16.h>
#include <math.h>

// S5 SSM layer. B_SZ=16, L=1024, H=256, P=256.
// 4 dispatches, all sized for >=16 waves/CU:
//   k_prep   : build W1T/W2T
//   k_g1scan : per-chunk GEMM1 (u@B_bar^T) -> LDS -> local scan -> XS + CEND
//   k_scanBC : per-chunk own exclusive carry (from CEND) + fixup XS
//   k_gemm2  : XS @ W2T^T + D*u -> out   (64x64 tiles, 1024 blocks)
#define BB     16
#define LSEQ   1024
#define HH     256
#define PP     256
#define MROWS  (BB*LSEQ)     // 16384
#define LC     32
#define NC     (LSEQ/LC)     // 32
#define NCHUNK (BB*NC)       // 512

// workspace byte offsets
#define OFF_W1T  0u          // [512][256] bf16: row 2p=Re(B_bar[p][.]), 2p+1=Im
#define OFF_W2T  262144u     // [256][512] bf16: row h, k=2p -> 2*C_re, 2p+1 -> -2*C_im
#define OFF_CEND 524288u     // [512][256] float2 chunk-end states
#define OFF_XS   1572864u    // [16384][512] bf16 x states (col 2p=re, 2p+1=im)
// total = 18,350,080 bytes (~17.5 MB)

#define XSTRIDE 520          // bf16 elems per LDS X row (512 + 8 pad)

typedef __attribute__((ext_vector_type(8))) short short8;
typedef __attribute__((ext_vector_type(4))) float floatx4;

__device__ __forceinline__ float bf2f(unsigned hs) {
    union { unsigned u; float f; } v; v.u = hs << 16; return v.f;
}
__device__ __forceinline__ unsigned short f2bs(float f) {
    __hip_bfloat16 h = __float2bfloat16(f);
    union { __hip_bfloat16 h; unsigned short s; } v; v.h = h; return v.s;
}
__device__ __forceinline__ unsigned packbf(float r, float i) {
    return (unsigned)f2bs(r) | ((unsigned)f2bs(i) << 16);
}
__device__ __forceinline__ void async16(const void* g, void* l) {
    __builtin_amdgcn_global_load_lds(
        (const __attribute__((address_space(1))) unsigned*)g,
        (__attribute__((address_space(3))) unsigned*)l, 16, 0, 0);
}
__device__ __forceinline__ float2 lam_pow(float lr, float li, float dtt) {
    float m = expf(lr * dtt);
    return make_float2(m * cosf(li * dtt), m * sinf(li * dtt));
}

// ---------------- prep: W1T (blocks 0..255) and W2T (blocks 256..511) ----------------
__global__ void k_prep(const float* __restrict__ Bm, const float* __restrict__ Cm,
                       const float* __restrict__ Lr, const float* __restrict__ Li,
                       const float* __restrict__ ls, char* __restrict__ ws) {
    int blk = blockIdx.x, t = threadIdx.x;
    if (blk < 256) {
        int p = blk, h = t;
        float lr = Lr[p], li = Li[p];
        float dt = expf(ls[p]);
        float2 lam = lam_pow(lr, li, dt);
        float den = lr * lr + li * li;
        float nr = lam.x - 1.0f, ni = lam.y;
        float cr = (nr * lr + ni * li) / den;       // (lam_bar-1)/Lambda
        float ci = (ni * lr - nr * li) / den;
        float br = Bm[(p * HH + h) * 2 + 0];
        float bi = Bm[(p * HH + h) * 2 + 1];
        unsigned short* w1 = (unsigned short*)(ws + OFF_W1T);
        w1[(2 * p) * 256 + h]     = f2bs(cr * br - ci * bi);
        w1[(2 * p + 1) * 256 + h] = f2bs(cr * bi + ci * br);
    } else {
        int h = blk - 256, p = t;
        float c_r = Cm[(h * PP + p) * 2 + 0];
        float c_i = Cm[(h * PP + p) * 2 + 1];
        ((unsigned*)(ws + OFF_W2T))[h * 256 + p] = packbf(2.0f * c_r, -2.0f * c_i);
    }
}

// ---------------- fused GEMM1 + local chunk scan (512 threads / 8 waves) ----------------
// One block per chunk: rows m0..m0+31, N=512, K=256. Each wave owns a 64-col slice.
__global__ __launch_bounds__(512, 4) void k_g1scan(
        const float* __restrict__ u, const float* __restrict__ Lr,
        const float* __restrict__ Li, const float* __restrict__ ls,
        char* __restrict__ ws) {
    __shared__ char smem[2048 + 33280];   // As 32x32 bf16 | Bs 512x32 bf16 UNION X 32x520 bf16
    unsigned*  As32 = (unsigned*)smem;
    char*      Bs   = smem + 2048;
    unsigned short* X = (unsigned short*)(smem + 2048);
    unsigned*  X32  = (unsigned*)(smem + 2048);
    const unsigned short* W1 = (const unsigned short*)(ws + OFF_W1T);
    const int tid = threadIdx.x, bc = blockIdx.x;
    const int wave = tid >> 6, lane = tid & 63;
    const int q = lane >> 4, rr = lane & 15;
    const int c4 = lane & 3, r4 = lane >> 2;
    const int m0 = bc * LC;

    floatx4 acc[2][4];
    #pragma unroll
    for (int i = 0; i < 2; ++i)
        #pragma unroll
        for (int j = 0; j < 4; ++j) acc[i][j] = (floatx4)0.0f;

    const int urow = tid >> 4, ucol2 = (tid & 15) * 2;   // A-stage: 2 fp32 per thread
    for (int k0 = 0; k0 < 256; k0 += 32) {
        __syncthreads();
        float2 v = *(const float2*)(u + (size_t)(m0 + urow) * 256 + k0 + ucol2);
        As32[urow * 16 + (tid & 15)] = packbf(v.x, v.y);
        #pragma unroll
        for (int t = wave; t < 32; t += 8)
            async16(W1 + (size_t)(t * 16 + r4) * 256 + k0 + c4 * 8,
                    Bs + t * 1024 + lane * 16);
        __syncthreads();
        short8 a0 = *(const short8*)((char*)As32 + rr * 64 + q * 16);
        short8 a1 = *(const short8*)((char*)As32 + (16 + rr) * 64 + q * 16);
        #pragma unroll
        for (int j = 0; j < 4; ++j) {
            short8 b = *(const short8*)(Bs + ((wave * 4 + j) * 16 + rr) * 64 + q * 16);
            acc[0][j] = __builtin_amdgcn_mfma_f32_16x16x32_bf16(a0, b, acc[0][j], 0, 0, 0);
            acc[1][j] = __builtin_amdgcn_mfma_f32_16x16x32_bf16(a1, b, acc[1][j], 0, 0, 0);
        }
    }
    __syncthreads();
    // dump Bu tile (32 x 512) into padded LDS X
    #pragma unroll
    for (int i = 0; i < 2; ++i)
        #pragma unroll
        for (int j = 0; j < 4; ++j)
            #pragma unroll
            for (int r0 = 0; r0 < 4; ++r0)
                X[(i * 16 + q * 4 + r0) * XSTRIDE + wave * 64 + j * 16 + rr] =
                    f2bs(acc[i][j][r0]);
    __syncthreads();

    // local chunk scan in LDS (threads 0..255; one channel pair each)
    if (tid < 256) {
        const int p = tid;
        const float2 lam = lam_pow(Lr[p], Li[p], expf(ls[p]));
        unsigned* xs32 = (unsigned*)(ws + OFF_XS);
        float xr = 0.0f, xi = 0.0f;
        for (int j = 0; j < LC; ++j) {
            unsigned cv = X32[j * (XSTRIDE / 2) + p];
            float br = bf2f(cv & 0xffffu), bi = bf2f(cv >> 16);
            float nr = fmaf(lam.x, xr, fmaf(-lam.y, xi, br));
            float ni = fmaf(lam.x, xi, fmaf(lam.y, xr, bi));
            xr = nr; xi = ni;
            xs32[(size_t)(m0 + j) * 256 + p] = packbf(xr, xi);
        }
        ((float2*)(ws + OFF_CEND))[bc * 256 + p] = make_float2(xr, xi);
    }
}

// ---------------- scanBC: own exclusive chunk carry + fixup XS ----------------
__global__ __launch_bounds__(256) void k_scanBC(
        const float* __restrict__ Lr, const float* __restrict__ Li,
        const float* __restrict__ ls, char* __restrict__ ws) {
    const int p = threadIdx.x, bc = blockIdx.x;       // 512 blocks
    const int b = bc >> 5, c = bc & (NC - 1);
    if (c == 0) return;                                // first chunk: carry = 0
    const float dt = expf(ls[p]);
    const float lr = Lr[p], li = Li[p];
    const float2 lam = lam_pow(lr, li, dt);
    const float2 g = lam_pow(lr, li, dt * (float)LC);  // lambda^LC
    const float2* cend = (const float2*)(ws + OFF_CEND);

    float sr = 0.0f, si = 0.0f;
    for (int cc = 0; cc < c; ++cc) {                   // block-uniform trip count
        float2 e = cend[(size_t)(b * NC + cc) * 256 + p];
        float nr = fmaf(g.x, sr, fmaf(-g.y, si, e.x));
        float ni = fmaf(g.x, si, fmaf(g.y, sr, e.y));
        sr = nr; si = ni;
    }

    float pr = lam.x, pi = lam.y;                      // lambda^{j+1}
    unsigned* xs32 = (unsigned*)(ws + OFF_XS);
    size_t idx = (size_t)bc * LC * 256 + p;
    for (int j = 0; j < LC; ++j) {
        float ar = pr * sr - pi * si;
        float ai = pr * si + pi * sr;
        unsigned v = xs32[idx];
        xs32[idx] = packbf(bf2f(v & 0xffffu) + ar, bf2f(v >> 16) + ai);
        float nr = pr * lam.x - pi * lam.y;
        pi = pr * lam.y + pi * lam.x; pr = nr;
        idx += 256;
    }
}

// ---------------- GEMM2: out = XS @ W2T^T + D*u  (BM=64, BN=64, 1024 blocks) ----------------
__global__ __launch_bounds__(256, 4) void k_gemm2(
        const char* __restrict__ ws_c, const float* __restrict__ D,
        const float* __restrict__ u, float* __restrict__ out) {
    __shared__ unsigned short As[64 * 32];
    __shared__ unsigned short Bs[64 * 32];
    const unsigned short* A = (const unsigned short*)(ws_c + OFF_XS);
    const unsigned short* W = (const unsigned short*)(ws_c + OFF_W2T);
    const int tid = threadIdx.x;
    const int wave = tid >> 6, lane = tid & 63;
    const int q = lane >> 4, rr = lane & 15;
    const int c4 = lane & 3, r4 = lane >> 2;
    const int wm = wave & 1, wn = wave >> 1;
    const int m0 = blockIdx.y * 64, n0 = blockIdx.x * 64;

    floatx4 acc[2][2];
    #pragma unroll
    for (int i = 0; i < 2; ++i)
        #pragma unroll
        for (int j = 0; j < 2; ++j) acc[i][j] = (floatx4)0.0f;

    for (int k0 = 0; k0 < 512; k0 += 32) {
        __syncthreads();
        async16(A + (size_t)(m0 + wave * 16 + r4) * 512 + k0 + c4 * 8,
                (char*)As + wave * 1024 + lane * 16);
        async16(W + (size_t)(n0 + wave * 16 + r4) * 512 + k0 + c4 * 8,
                (char*)Bs + wave * 1024 + lane * 16);
        __syncthreads();
        short8 a[2], b[2];
        #pragma unroll
        for (int i = 0; i < 2; ++i)
            a[i] = *(const short8*)((const char*)As + ((wm * 2 + i) * 16 + rr) * 64 + q * 16);
        #pragma unroll
        for (int j = 0; j < 2; ++j)
            b[j] = *(const short8*)((const char*)Bs + ((wn * 2 + j) * 16 + rr) * 64 + q * 16);
        #pragma unroll
        for (int i = 0; i < 2; ++i)
            #pragma unroll
            for (int j = 0; j < 2; ++j)
                acc[i][j] = __builtin_amdgcn_mfma_f32_16x16x32_bf16(a[i], b[j], acc[i][j], 0, 0, 0);
    }

    #pragma unroll
    for (int i = 0; i < 2; ++i) {
        int mbase = m0 + wm * 32 + i * 16 + q * 4;
        #pragma unroll
        for (int j = 0; j < 2; ++j) {
            int col = n0 + wn * 32 + j * 16 + rr;
            #pragma unroll
            for (int r0 = 0; r0 < 4; ++r0) {
                int row = mbase + r0;
                size_t gi = (size_t)row * 256 + col;
                out[gi] = acc[i][j][r0] + D[col] * u[gi];
            }
        }
    }
}

extern "C" void kernel_launch(void* const* d_in, const int* in_sizes, int n_in,
                              void* d_out, int out_size, void* d_ws, size_t ws_size,
                              hipStream_t stream) {
    const float* u  = (const float*)d_in[0];
    const float* Lr = (const float*)d_in[1];
    const float* Li = (const float*)d_in[2];
    const float* Bm = (const float*)d_in[3];
    const float* Cm = (const float*)d_in[4];
    const float* D  = (const float*)d_in[5];
    const float* ls = (const float*)d_in[6];
    float* out = (float*)d_out;
    char* ws = (char*)d_ws;

    k_prep<<<512, 256, 0, stream>>>(Bm, Cm, Lr, Li, ls, ws);
    k_g1scan<<<NCHUNK, 512, 0, stream>>>(u, Lr, Li, ls, ws);
    k_scanBC<<<NCHUNK, 256, 0, stream>>>(Lr, Li, ls, ws);
    k_gemm2<<<dim3(4, MROWS / 64), 256, 0, stream>>>(ws, D, u, out);
}